// Round 3
// baseline (2661.909 us; speedup 1.0000x reference)
//
#include <hip/hip_runtime.h>
#include <hip/hip_bf16.h>

// Problem constants
// V=50000, D=300, R=256, SA=256, B=512, L=128

typedef short bf16x8 __attribute__((ext_vector_type(8)));
typedef float f32x4  __attribute__((ext_vector_type(4)));

__device__ __forceinline__ unsigned short f2bf(float f){
  unsigned int u = __float_as_uint(f);
  u += 0x7FFFu + ((u >> 16) & 1u);           // RNE
  return (unsigned short)(u >> 16);
}
__device__ __forceinline__ float bf2f(unsigned short s){
  return __uint_as_float(((unsigned int)s) << 16);
}
#define MFMA(a,b,c) __builtin_amdgcn_mfma_f32_16x16x32_bf16((a),(b),(c),0,0,0)

// ---------------------------------------------------------------------------
// Weight repack: fragment-linear bf16. Fragment (nt,kt): 64 lanes x 8 bf16,
// element j of lane l = W[kt*32 + 8*(l>>4)+j][nt*16 + (l&15)].
// Buffers: genf[16nt][10kt], w12f[32nt][8kt] (Wss1|Wss2),
// wrs12f[32nt][8kt] (Wrs1|Wrs2), tr1f[16nt][8kt],
// t2wf[16nt][16kt] (k<256: trans_r2^T, k>=256: trans_wildcard)
// ---------------------------------------------------------------------------
__global__ void prep_weights(
    const float* __restrict__ Wss1, const float* __restrict__ Wss2,
    const float* __restrict__ Wrs1, const float* __restrict__ Wrs2,
    const float* __restrict__ tr1,  const float* __restrict__ tr2,
    const float* __restrict__ wild, const float* __restrict__ gen,
    unsigned short* __restrict__ genf,   unsigned short* __restrict__ w12f,
    unsigned short* __restrict__ wrs12f, unsigned short* __restrict__ tr1f,
    unsigned short* __restrict__ t2wf)
{
  int t = blockIdx.x * blockDim.x + threadIdx.x;
  int lane = t & 63;
  int fi = t >> 6;
  if (fi >= 1056) return;
  int li = lane & 15, lk = lane >> 4;
  bf16x8 o;
  unsigned short* dst;
  if (fi < 160) {                       // genf: embed_r_gen (300x256), K padded to 320
    int nt = fi / 10, kt = fi - nt*10;
    int n = nt*16 + li;
    #pragma unroll
    for (int j=0;j<8;j++){ int k = kt*32 + lk*8 + j;
      o[j] = (k < 300) ? (short)f2bf(gen[k*256 + n]) : (short)0; }
    dst = genf + fi*512 + lane*8;
  } else if (fi < 416) {                // w12f: [Wss1 | Wss2]  K=256, N=512
    int f = fi - 160; int nt = f >> 3, kt = f & 7;
    int n = nt*16 + li;
    #pragma unroll
    for (int j=0;j<8;j++){ int k = kt*32 + lk*8 + j;
      float v = (n < 256) ? Wss1[k*256 + n] : Wss2[k*256 + (n-256)];
      o[j] = (short)f2bf(v); }
    dst = w12f + f*512 + lane*8;
  } else if (fi < 672) {                // wrs12f: [Wrs1 | Wrs2]
    int f = fi - 416; int nt = f >> 3, kt = f & 7;
    int n = nt*16 + li;
    #pragma unroll
    for (int j=0;j<8;j++){ int k = kt*32 + lk*8 + j;
      float v = (n < 256) ? Wrs1[k*256 + n] : Wrs2[k*256 + (n-256)];
      o[j] = (short)f2bf(v); }
    dst = wrs12f + f*512 + lane*8;
  } else if (fi < 800) {                // tr1f: trans_r1 (SA x R)
    int f = fi - 672; int nt = f >> 3, kt = f & 7;
    int n = nt*16 + li;
    #pragma unroll
    for (int j=0;j<8;j++){ int k = kt*32 + lk*8 + j;
      o[j] = (short)f2bf(tr1[k*256 + n]); }
    dst = tr1f + f*512 + lane*8;
  } else {                              // t2wf: [trans_r2^T ; wildcard]  K=512, N=256
    int f = fi - 800; int nt = f >> 4, kt = f & 15;
    int n = nt*16 + li;
    #pragma unroll
    for (int j=0;j<8;j++){ int k = kt*32 + lk*8 + j;
      float v = (k < 256) ? tr2[n*256 + k] : wild[(k-256)*256 + n];
      o[j] = (short)f2bf(v); }
    dst = t2wf + f*512 + lane*8;
  }
  *reinterpret_cast<bf16x8*>(dst) = o;
}

// ---------------------------------------------------------------------------
// Lseq = beta*embed_r[ids] + (1-beta)*tanh(emb[ids] @ embed_r_gen)   -> bf16
// M=65536 rows, Mtile=64 per block, N=256, K=300 (padded 320)
// ---------------------------------------------------------------------------
__global__ __launch_bounds__(256, 1)
void embed_lseq(const int* __restrict__ ids, const float* __restrict__ emb,
                const float* __restrict__ embr, const float* __restrict__ beta,
                const unsigned short* __restrict__ genf,
                unsigned short* __restrict__ Lseq)
{
  __shared__ unsigned short As[64*336];   // 64 rows x 320 bf16, stride 336
  __shared__ int toks[64];
  int tid = threadIdx.x;
  int m0 = blockIdx.x * 64;
  if (tid < 64) toks[tid] = ids[m0 + tid];
  __syncthreads();
  for (int e = tid; e < 64*320; e += 256){
    int r = e / 320, k = e - r*320;
    float v = (k < 300) ? emb[toks[r]*300 + k] : 0.f;
    As[r*336 + k] = f2bf(v);
  }
  __syncthreads();
  int w = tid >> 6, lane = tid & 63, li = lane & 15, lk = lane >> 4;
  f32x4 acc[4][4];
  #pragma unroll
  for (int nt=0;nt<4;nt++)
    #pragma unroll
    for (int mt=0;mt<4;mt++) acc[nt][mt] = (f32x4){0.f,0.f,0.f,0.f};

  for (int kt=0; kt<10; kt++){
    bf16x8 af[4];
    #pragma unroll
    for (int mt=0;mt<4;mt++)
      af[mt] = *reinterpret_cast<const bf16x8*>(&As[(mt*16+li)*336 + kt*32 + lk*8]);
    #pragma unroll
    for (int nt=0;nt<4;nt++){
      int n0 = w*4 + nt;
      bf16x8 bf = *reinterpret_cast<const bf16x8*>(&genf[((n0*10+kt)*64 + lane)*8]);
      #pragma unroll
      for (int mt=0;mt<4;mt++) acc[nt][mt] = MFMA(af[mt], bf, acc[nt][mt]);
    }
  }
  #pragma unroll
  for (int nt=0;nt<4;nt++){
    int col = (w*4+nt)*16 + li;
    float be = beta[col];
    #pragma unroll
    for (int mt=0;mt<4;mt++){
      #pragma unroll
      for (int reg=0;reg<4;reg++){
        int row = mt*16 + lk*4 + reg;
        float lg = tanhf(acc[nt][mt][reg]);
        float er = embr[toks[row]*256 + col];
        float ls = er*be + lg*(1.f - be);
        Lseq[(m0+row)*256 + col] = f2bf(ls);
      }
    }
  }
}

// ---------------------------------------------------------------------------
// U12 = Lseq @ [Wrs1|Wrs2] + [bs1|bs2]   (65536 x 512, f32)
// ---------------------------------------------------------------------------
__global__ __launch_bounds__(256, 1)
void u12_gemm(const unsigned short* __restrict__ Lseq,
              const unsigned short* __restrict__ wrs12f,
              const float* __restrict__ bs1, const float* __restrict__ bs2,
              float* __restrict__ U12)
{
  __shared__ unsigned short As[64*264];   // 64 rows x 256 bf16, stride 264
  int tid = threadIdx.x, m0 = blockIdx.x*64;
  for (int c = tid; c < 64*32; c += 256){
    int r = c >> 5, ck = c & 31;
    *reinterpret_cast<bf16x8*>(&As[r*264 + ck*8]) =
      *reinterpret_cast<const bf16x8*>(&Lseq[(m0+r)*256 + ck*8]);
  }
  __syncthreads();
  int w = tid >> 6, lane = tid & 63, li = lane & 15, lk = lane >> 4;
  f32x4 acc[8][4];
  #pragma unroll
  for (int nt=0;nt<8;nt++)
    #pragma unroll
    for (int mt=0;mt<4;mt++) acc[nt][mt] = (f32x4){0.f,0.f,0.f,0.f};

  for (int kt=0;kt<8;kt++){
    bf16x8 af[4];
    #pragma unroll
    for (int mt=0;mt<4;mt++)
      af[mt] = *reinterpret_cast<const bf16x8*>(&As[(mt*16+li)*264 + kt*32 + lk*8]);
    #pragma unroll
    for (int nt=0;nt<8;nt++){
      int n0 = w*8 + nt;
      bf16x8 bf = *reinterpret_cast<const bf16x8*>(&wrs12f[((n0*8+kt)*64+lane)*8]);
      #pragma unroll
      for (int mt=0;mt<4;mt++) acc[nt][mt] = MFMA(af[mt], bf, acc[nt][mt]);
    }
  }
  #pragma unroll
  for (int nt=0;nt<8;nt++){
    int col = (w*8+nt)*16 + li;
    float bias = (col < 256) ? bs1[col] : bs2[col-256];
    #pragma unroll
    for (int mt=0;mt<4;mt++){
      #pragma unroll
      for (int reg=0;reg<4;reg++){
        int row = mt*16 + lk*4 + reg;
        U12[(m0+row)*512 + col] = acc[nt][mt][reg] + bias;
      }
    }
  }
}

// ---------------------------------------------------------------------------
// Recurrent scan: 32 blocks x 16 batch rows, 128 steps, no grid sync.
// Per step: [zt|rt]=sigmoid(U12_t + h@[Wss1|Wss2]); hbar=(1-rt)h1+rt*h;
// Rv=hbar@tr1; hid=relu([Lt*Rv|hbar]@[tr2^T;wild]); h=(1-zt)h+zt*hid
// ---------------------------------------------------------------------------
__global__ __launch_bounds__(256, 1)
void scan_kernel(const unsigned short* __restrict__ Lseq,
                 const float* __restrict__ U12,
                 const unsigned short* __restrict__ w12f,
                 const unsigned short* __restrict__ tr1f,
                 const unsigned short* __restrict__ t2wf,
                 const float* __restrict__ h1,
                 float* __restrict__ out)
{
  __shared__ float hS[16][260];            // h state (f32)
  __shared__ float zS[16][260];            // z gate
  __shared__ float tS[16][260];            // hbar, then Lt*Rv (aliased)
  __shared__ unsigned short ltS[16*256];   // Lt tile (bf16)
  __shared__ float h1S[256];
  int tid = threadIdx.x;
  int w = tid >> 6, lane = tid & 63, li = lane & 15, lk = lane >> 4;
  int b0 = blockIdx.x * 16;

  for (int i = tid; i < 256; i += 256) h1S[i] = h1[i];
  for (int i = tid; i < 16*256; i += 256){ int r = i >> 8, s = i & 255;
    hS[r][s] = (s == 0) ? 1.f : 0.f; }
  __syncthreads();

  for (int t = 0; t < 128; t++){
    // cooperative Lt tile load (16 rows x 256 bf16)
    for (int c = tid; c < 512; c += 256){
      int r = c >> 5, ck = c & 31;
      *reinterpret_cast<bf16x8*>(&ltS[r*256 + ck*8]) =
        *reinterpret_cast<const bf16x8*>(&Lseq[((b0+r)*128 + t)*256 + ck*8]);
    }
    // U12 preload (issued early, flies under frag builds)
    float u[8][4];
    #pragma unroll
    for (int nt=0;nt<8;nt++){
      int col = (w*8+nt)*16 + li;
      #pragma unroll
      for (int reg=0;reg<4;reg++)
        u[nt][reg] = U12[((b0 + lk*4 + reg)*128 + t)*512 + col];
    }
    // h A-fragments
    bf16x8 ah[8];
    #pragma unroll
    for (int kt=0;kt<8;kt++){
      const float* hp = &hS[li][kt*32 + lk*8];
      bf16x8 a;
      #pragma unroll
      for (int j=0;j<8;j++) a[j] = (short)f2bf(hp[j]);
      ah[kt] = a;
    }
    // stage 1: gates. wave w covers concat cols [128w,128w+128)
    #pragma unroll
    for (int nt=0;nt<8;nt++){
      int n0 = w*8 + nt;
      f32x4 acc = { u[nt][0], u[nt][1], u[nt][2], u[nt][3] };
      #pragma unroll
      for (int kt=0;kt<8;kt++){
        bf16x8 bw = *reinterpret_cast<const bf16x8*>(&w12f[((n0*8+kt)*64+lane)*8]);
        acc = MFMA(ah[kt], bw, acc);
      }
      int col = n0*16 + li;
      #pragma unroll
      for (int reg=0;reg<4;reg++){
        int row = lk*4 + reg;
        float g = 1.f / (1.f + expf(-acc[reg]));
        if (col < 256) { zS[row][col] = g; }
        else { int s = col - 256;
          tS[row][s] = (1.f - g)*h1S[s] + g*hS[row][s]; }
      }
    }
    __syncthreads();
    // hbar A-fragments (kept in regs through stage 4)
    bf16x8 ab[8];
    #pragma unroll
    for (int kt=0;kt<8;kt++){
      const float* hp = &tS[li][kt*32 + lk*8];
      bf16x8 a;
      #pragma unroll
      for (int j=0;j<8;j++) a[j] = (short)f2bf(hp[j]);
      ab[kt] = a;
    }
    __syncthreads();   // everyone done reading hbar; tS can be reused
    // stage 3: Rv = hbar@tr1, then tS <- Lt*Rv
    #pragma unroll
    for (int nt=0;nt<4;nt++){
      int n0 = w*4 + nt;
      f32x4 acc = (f32x4){0.f,0.f,0.f,0.f};
      #pragma unroll
      for (int kt=0;kt<8;kt++){
        bf16x8 bw = *reinterpret_cast<const bf16x8*>(&tr1f[((n0*8+kt)*64+lane)*8]);
        acc = MFMA(ab[kt], bw, acc);
      }
      int r = n0*16 + li;
      #pragma unroll
      for (int reg=0;reg<4;reg++){
        int row = lk*4 + reg;
        tS[row][r] = bf2f(ltS[row*256 + r]) * acc[reg];
      }
    }
    __syncthreads();
    // LtRv A-fragments
    bf16x8 al[8];
    #pragma unroll
    for (int kt=0;kt<8;kt++){
      const float* hp = &tS[li][kt*32 + lk*8];
      bf16x8 a;
      #pragma unroll
      for (int j=0;j<8;j++) a[j] = (short)f2bf(hp[j]);
      al[kt] = a;
    }
    // stage 4: hid = [LtRv|hbar] @ [tr2^T ; wild], relu, blend, write
    #pragma unroll
    for (int nt=0;nt<4;nt++){
      int n0 = w*4 + nt;
      f32x4 acc = (f32x4){0.f,0.f,0.f,0.f};
      #pragma unroll
      for (int kt=0;kt<8;kt++){
        bf16x8 bw = *reinterpret_cast<const bf16x8*>(&t2wf[((n0*16+kt)*64+lane)*8]);
        acc = MFMA(al[kt], bw, acc);
      }
      #pragma unroll
      for (int kt=0;kt<8;kt++){
        bf16x8 bw = *reinterpret_cast<const bf16x8*>(&t2wf[((n0*16+8+kt)*64+lane)*8]);
        acc = MFMA(ab[kt], bw, acc);
      }
      int s = n0*16 + li;
      #pragma unroll
      for (int reg=0;reg<4;reg++){
        int row = lk*4 + reg;
        float hid = fmaxf(acc[reg], 0.f);
        float z = zS[row][s];
        float hn = (1.f - z)*hS[row][s] + z*hid;
        hS[row][s] = hn;
        out[((b0+row)*128 + t)*256 + s] = hn;
      }
    }
    __syncthreads();
  }
}

// ---------------------------------------------------------------------------
extern "C" void kernel_launch(void* const* d_in, const int* in_sizes, int n_in,
                              void* d_out, int out_size, void* d_ws, size_t ws_size,
                              hipStream_t stream)
{
  const int*   ids  = (const int*)  d_in[0];
  // d_in[1] lengths: unused by forward
  const float* emb  = (const float*)d_in[2];
  const float* embr = (const float*)d_in[3];
  const float* gen  = (const float*)d_in[4];
  const float* Wss1 = (const float*)d_in[5];
  const float* Wrs1 = (const float*)d_in[6];
  const float* bs1  = (const float*)d_in[7];
  const float* Wss2 = (const float*)d_in[8];
  const float* Wrs2 = (const float*)d_in[9];
  const float* bs2  = (const float*)d_in[10];
  const float* beta = (const float*)d_in[11];
  const float* wild = (const float*)d_in[12];
  const float* tr1  = (const float*)d_in[13];
  const float* tr2  = (const float*)d_in[14];
  const float* h1   = (const float*)d_in[15];
  float* out = (float*)d_out;

  char* ws = (char*)d_ws;
  unsigned short* genf   = (unsigned short*)(ws + 0);         // 163840 B
  unsigned short* w12f   = (unsigned short*)(ws + 163840);    // 262144 B
  unsigned short* wrs12f = (unsigned short*)(ws + 425984);    // 262144 B
  unsigned short* tr1f   = (unsigned short*)(ws + 688128);    // 131072 B
  unsigned short* t2wf   = (unsigned short*)(ws + 819200);    // 262144 B
  unsigned short* LseqB  = (unsigned short*)(ws + 1081344);   // 33554432 B
  float*          U12    = (float*)         (ws + 34635776);  // 134217728 B
  // total ws use: 168,853,504 bytes

  prep_weights<<<264, 256, 0, stream>>>(Wss1, Wss2, Wrs1, Wrs2, tr1, tr2, wild, gen,
                                        genf, w12f, wrs12f, tr1f, t2wf);
  embed_lseq<<<1024, 256, 0, stream>>>(ids, emb, embr, beta, genf, LseqB);
  u12_gemm<<<1024, 256, 0, stream>>>(LseqB, wrs12f, bs1, bs2, U12);
  scan_kernel<<<32, 256, 0, stream>>>(LseqB, U12, w12f, tr1f, t2wf, h1, out);
}

// Round 5
// 2024.168 us; speedup vs baseline: 1.3151x; 1.3151x over previous
//
#include <hip/hip_runtime.h>
#include <hip/hip_bf16.h>

// Problem constants
// V=50000, D=300, R=256, SA=256, B=512, L=128

typedef short bf16x8 __attribute__((ext_vector_type(8)));
typedef float f32x4  __attribute__((ext_vector_type(4)));

__device__ __forceinline__ unsigned short f2bf(float f){
  unsigned int u = __float_as_uint(f);
  u += 0x7FFFu + ((u >> 16) & 1u);           // RNE
  return (unsigned short)(u >> 16);
}
__device__ __forceinline__ float bf2f(unsigned short s){
  return __uint_as_float(((unsigned int)s) << 16);
}
#define MFMA(a,b,c) __builtin_amdgcn_mfma_f32_16x16x32_bf16((a),(b),(c),0,0,0)

// ---------------------------------------------------------------------------
// Weight repack: fragment-linear bf16. Fragment (nt,kt): 64 lanes x 8 bf16,
// element j of lane l = W[kt*32 + 8*(l>>4)+j][nt*16 + (l&15)].
// ---------------------------------------------------------------------------
__global__ void prep_weights(
    const float* __restrict__ Wss1, const float* __restrict__ Wss2,
    const float* __restrict__ Wrs1, const float* __restrict__ Wrs2,
    const float* __restrict__ tr1,  const float* __restrict__ tr2,
    const float* __restrict__ wild, const float* __restrict__ gen,
    unsigned short* __restrict__ genf,   unsigned short* __restrict__ w12f,
    unsigned short* __restrict__ wrs12f, unsigned short* __restrict__ tr1f,
    unsigned short* __restrict__ t2wf)
{
  int t = blockIdx.x * blockDim.x + threadIdx.x;
  int lane = t & 63;
  int fi = t >> 6;
  if (fi >= 1056) return;
  int li = lane & 15, lk = lane >> 4;
  bf16x8 o;
  unsigned short* dst;
  if (fi < 160) {                       // genf: embed_r_gen (300x256), K padded to 320
    int nt = fi / 10, kt = fi - nt*10;
    int n = nt*16 + li;
    #pragma unroll
    for (int j=0;j<8;j++){ int k = kt*32 + lk*8 + j;
      o[j] = (k < 300) ? (short)f2bf(gen[k*256 + n]) : (short)0; }
    dst = genf + fi*512 + lane*8;
  } else if (fi < 416) {                // w12f: [Wss1 | Wss2]  K=256, N=512
    int f = fi - 160; int nt = f >> 3, kt = f & 7;
    int n = nt*16 + li;
    #pragma unroll
    for (int j=0;j<8;j++){ int k = kt*32 + lk*8 + j;
      float v = (n < 256) ? Wss1[k*256 + n] : Wss2[k*256 + (n-256)];
      o[j] = (short)f2bf(v); }
    dst = w12f + f*512 + lane*8;
  } else if (fi < 672) {                // wrs12f: [Wrs1 | Wrs2]
    int f = fi - 416; int nt = f >> 3, kt = f & 7;
    int n = nt*16 + li;
    #pragma unroll
    for (int j=0;j<8;j++){ int k = kt*32 + lk*8 + j;
      float v = (n < 256) ? Wrs1[k*256 + n] : Wrs2[k*256 + (n-256)];
      o[j] = (short)f2bf(v); }
    dst = wrs12f + f*512 + lane*8;
  } else if (fi < 800) {                // tr1f: trans_r1 (SA x R)
    int f = fi - 672; int nt = f >> 3, kt = f & 7;
    int n = nt*16 + li;
    #pragma unroll
    for (int j=0;j<8;j++){ int k = kt*32 + lk*8 + j;
      o[j] = (short)f2bf(tr1[k*256 + n]); }
    dst = tr1f + f*512 + lane*8;
  } else {                              // t2wf: [trans_r2^T ; wildcard]  K=512, N=256
    int f = fi - 800; int nt = f >> 4, kt = f & 15;
    int n = nt*16 + li;
    #pragma unroll
    for (int j=0;j<8;j++){ int k = kt*32 + lk*8 + j;
      float v = (k < 256) ? tr2[n*256 + k] : wild[(k-256)*256 + n];
      o[j] = (short)f2bf(v); }
    dst = t2wf + f*512 + lane*8;
  }
  *reinterpret_cast<bf16x8*>(dst) = o;
}

// ---------------------------------------------------------------------------
// Lseq = beta*embed_r[ids] + (1-beta)*tanh(emb[ids] @ embed_r_gen)   -> bf16
// ---------------------------------------------------------------------------
__global__ __launch_bounds__(256, 1)
void embed_lseq(const int* __restrict__ ids, const float* __restrict__ emb,
                const float* __restrict__ embr, const float* __restrict__ beta,
                const unsigned short* __restrict__ genf,
                unsigned short* __restrict__ Lseq)
{
  __shared__ unsigned short As[64*336];   // 64 rows x 320 bf16, stride 336
  __shared__ int toks[64];
  int tid = threadIdx.x;
  int m0 = blockIdx.x * 64;
  if (tid < 64) toks[tid] = ids[m0 + tid];
  __syncthreads();
  for (int e = tid; e < 64*320; e += 256){
    int r = e / 320, k = e - r*320;
    float v = (k < 300) ? emb[toks[r]*300 + k] : 0.f;
    As[r*336 + k] = f2bf(v);
  }
  __syncthreads();
  int w = tid >> 6, lane = tid & 63, li = lane & 15, lk = lane >> 4;
  f32x4 acc[4][4];
  #pragma unroll
  for (int nt=0;nt<4;nt++)
    #pragma unroll
    for (int mt=0;mt<4;mt++) acc[nt][mt] = (f32x4){0.f,0.f,0.f,0.f};

  for (int kt=0; kt<10; kt++){
    bf16x8 af[4];
    #pragma unroll
    for (int mt=0;mt<4;mt++)
      af[mt] = *reinterpret_cast<const bf16x8*>(&As[(mt*16+li)*336 + kt*32 + lk*8]);
    #pragma unroll
    for (int nt=0;nt<4;nt++){
      int n0 = w*4 + nt;
      bf16x8 bf = *reinterpret_cast<const bf16x8*>(&genf[((n0*10+kt)*64 + lane)*8]);
      #pragma unroll
      for (int mt=0;mt<4;mt++) acc[nt][mt] = MFMA(af[mt], bf, acc[nt][mt]);
    }
  }
  #pragma unroll
  for (int nt=0;nt<4;nt++){
    int col = (w*4+nt)*16 + li;
    float be = beta[col];
    #pragma unroll
    for (int mt=0;mt<4;mt++){
      #pragma unroll
      for (int reg=0;reg<4;reg++){
        int row = mt*16 + lk*4 + reg;
        float lg = tanhf(acc[nt][mt][reg]);
        float er = embr[toks[row]*256 + col];
        float ls = er*be + lg*(1.f - be);
        Lseq[(m0+row)*256 + col] = f2bf(ls);
      }
    }
  }
}

// ---------------------------------------------------------------------------
// U12 = Lseq @ [Wrs1|Wrs2] + [bs1|bs2]   (65536 x 512, f32)
// ---------------------------------------------------------------------------
__global__ __launch_bounds__(256, 1)
void u12_gemm(const unsigned short* __restrict__ Lseq,
              const unsigned short* __restrict__ wrs12f,
              const float* __restrict__ bs1, const float* __restrict__ bs2,
              float* __restrict__ U12)
{
  __shared__ unsigned short As[64*264];   // 64 rows x 256 bf16, stride 264
  int tid = threadIdx.x, m0 = blockIdx.x*64;
  for (int c = tid; c < 64*32; c += 256){
    int r = c >> 5, ck = c & 31;
    *reinterpret_cast<bf16x8*>(&As[r*264 + ck*8]) =
      *reinterpret_cast<const bf16x8*>(&Lseq[(m0+r)*256 + ck*8]);
  }
  __syncthreads();
  int w = tid >> 6, lane = tid & 63, li = lane & 15, lk = lane >> 4;
  f32x4 acc[8][4];
  #pragma unroll
  for (int nt=0;nt<8;nt++)
    #pragma unroll
    for (int mt=0;mt<4;mt++) acc[nt][mt] = (f32x4){0.f,0.f,0.f,0.f};

  for (int kt=0;kt<8;kt++){
    bf16x8 af[4];
    #pragma unroll
    for (int mt=0;mt<4;mt++)
      af[mt] = *reinterpret_cast<const bf16x8*>(&As[(mt*16+li)*264 + kt*32 + lk*8]);
    #pragma unroll
    for (int nt=0;nt<8;nt++){
      int n0 = w*8 + nt;
      bf16x8 bf = *reinterpret_cast<const bf16x8*>(&wrs12f[((n0*8+kt)*64+lane)*8]);
      #pragma unroll
      for (int mt=0;mt<4;mt++) acc[nt][mt] = MFMA(af[mt], bf, acc[nt][mt]);
    }
  }
  #pragma unroll
  for (int nt=0;nt<8;nt++){
    int col = (w*8+nt)*16 + li;
    float bias = (col < 256) ? bs1[col] : bs2[col-256];
    #pragma unroll
    for (int mt=0;mt<4;mt++){
      #pragma unroll
      for (int reg=0;reg<4;reg++){
        int row = mt*16 + lk*4 + reg;
        U12[(m0+row)*512 + col] = acc[nt][mt][reg] + bias;
      }
    }
  }
}

// ---------------------------------------------------------------------------
// Recurrent scan v2: 32 blocks x 512 threads (8 waves), 16 batch rows/block.
// Per-wave work halved vs v1; bf16 shadow state kills f2bf repacks;
// 3 barriers/step; U12/Lt prefetched one step ahead.
// wave w: stage1 nt in w*4..w*4+3 (gate cols w*64..w*64+63)
//         stage3/4 nt in w*2..w*2+1 (cols w*32..w*32+31)
// ---------------------------------------------------------------------------
__global__ __launch_bounds__(512, 2)
void scan_kernel(const unsigned short* __restrict__ Lseq,
                 const float* __restrict__ U12,
                 const unsigned short* __restrict__ w12f,
                 const unsigned short* __restrict__ tr1f,
                 const unsigned short* __restrict__ t2wf,
                 const float* __restrict__ h1,
                 float* __restrict__ out)
{
  __shared__ float hS[16][260];            // h state, f32 (exact blend)
  __shared__ float zS[16][260];            // z gate, f32
  __shared__ unsigned short hBf[16][264];  // h state, bf16 shadow (MFMA A)
  __shared__ unsigned short hbS[16][264];  // hbar, bf16
  __shared__ unsigned short rvS[16][264];  // Lt*Rv, bf16
  __shared__ unsigned short ltS[16*256];   // Lt tile, bf16
  __shared__ float h1S[256];
  int tid = threadIdx.x;
  int w = tid >> 6, lane = tid & 63, li = lane & 15, lk = lane >> 4;
  int b0 = blockIdx.x * 16;

  for (int i = tid; i < 256; i += 512) h1S[i] = h1[i];
  for (int i = tid; i < 16*256; i += 512){ int r = i >> 8, s = i & 255;
    float v = (s == 0) ? 1.f : 0.f;
    hS[r][s] = v; hBf[r][s] = f2bf(v); }

  // prefetch t=0: Lt (one 16B chunk/thread) and U12 (16 f32/lane)
  int ltRow = tid >> 5, ltCk = tid & 31;
  bf16x8 ltReg = *reinterpret_cast<const bf16x8*>(
      &Lseq[((b0 + ltRow)*128 + 0)*256 + ltCk*8]);
  float uPre[4][4];
  #pragma unroll
  for (int nt=0;nt<4;nt++){
    int col = (w*4+nt)*16 + li;
    #pragma unroll
    for (int reg=0;reg<4;reg++)
      uPre[nt][reg] = U12[((b0 + lk*4 + reg)*128 + 0)*512 + col];
  }
  __syncthreads();

  for (int t = 0; t < 128; t++){
    // commit prefetched Lt/U12; issue prefetch for t+1
    *reinterpret_cast<bf16x8*>(&ltS[ltRow*256 + ltCk*8]) = ltReg;
    float u[4][4];
    #pragma unroll
    for (int nt=0;nt<4;nt++)
      #pragma unroll
      for (int reg=0;reg<4;reg++) u[nt][reg] = uPre[nt][reg];
    int tn = (t < 127) ? t+1 : 127;
    ltReg = *reinterpret_cast<const bf16x8*>(
        &Lseq[((b0 + ltRow)*128 + tn)*256 + ltCk*8]);
    #pragma unroll
    for (int nt=0;nt<4;nt++){
      int col = (w*4+nt)*16 + li;
      #pragma unroll
      for (int reg=0;reg<4;reg++)
        uPre[nt][reg] = U12[((b0 + lk*4 + reg)*128 + tn)*512 + col];
    }
    // h A-fragments from bf16 shadow (direct b128 reads, no cvt)
    bf16x8 ah[8];
    #pragma unroll
    for (int kt=0;kt<8;kt++)
      ah[kt] = *reinterpret_cast<const bf16x8*>(&hBf[li][kt*32 + lk*8]);
    // stage 1: gates. wave w covers concat cols [64w, 64w+64)
    #pragma unroll
    for (int nt=0;nt<4;nt++){
      int n0 = w*4 + nt;
      f32x4 acc = { u[nt][0], u[nt][1], u[nt][2], u[nt][3] };
      #pragma unroll
      for (int kt=0;kt<8;kt++){
        bf16x8 bw = *reinterpret_cast<const bf16x8*>(&w12f[((n0*8+kt)*64+lane)*8]);
        acc = MFMA(ah[kt], bw, acc);
      }
      int col = n0*16 + li;          // wave-uniform branch: w<4 -> z, w>=4 -> hbar
      #pragma unroll
      for (int reg=0;reg<4;reg++){
        int row = lk*4 + reg;
        float g = 1.f / (1.f + expf(-acc[reg]));
        if (col < 256) { zS[row][col] = g; }
        else { int s = col - 256;
          float hb = (1.f - g)*h1S[s] + g*hS[row][s];
          hbS[row][s] = f2bf(hb); }
      }
    }
    __syncthreads();                 // bar1: hbar + ltS visible
    // hbar A-fragments
    bf16x8 ab[8];
    #pragma unroll
    for (int kt=0;kt<8;kt++)
      ab[kt] = *reinterpret_cast<const bf16x8*>(&hbS[li][kt*32 + lk*8]);
    // stage 3: Rv = hbar@tr1, then rvS <- Lt*Rv (bf16)
    #pragma unroll
    for (int nt=0;nt<2;nt++){
      int n0 = w*2 + nt;
      f32x4 acc = (f32x4){0.f,0.f,0.f,0.f};
      #pragma unroll
      for (int kt=0;kt<8;kt++){
        bf16x8 bw = *reinterpret_cast<const bf16x8*>(&tr1f[((n0*8+kt)*64+lane)*8]);
        acc = MFMA(ab[kt], bw, acc);
      }
      int r = n0*16 + li;
      #pragma unroll
      for (int reg=0;reg<4;reg++){
        int row = lk*4 + reg;
        rvS[row][r] = f2bf(bf2f(ltS[row*256 + r]) * acc[reg]);
      }
    }
    __syncthreads();                 // bar2: rvS visible
    // LtRv A-fragments
    bf16x8 al[8];
    #pragma unroll
    for (int kt=0;kt<8;kt++)
      al[kt] = *reinterpret_cast<const bf16x8*>(&rvS[li][kt*32 + lk*8]);
    // stage 4: hid = [LtRv|hbar] @ [tr2^T ; wild], relu, blend, write
    #pragma unroll
    for (int nt=0;nt<2;nt++){
      int n0 = w*2 + nt;
      f32x4 acc = (f32x4){0.f,0.f,0.f,0.f};
      #pragma unroll
      for (int kt=0;kt<8;kt++){
        bf16x8 bw = *reinterpret_cast<const bf16x8*>(&t2wf[((n0*16+kt)*64+lane)*8]);
        acc = MFMA(al[kt], bw, acc);
      }
      #pragma unroll
      for (int kt=0;kt<8;kt++){
        bf16x8 bw = *reinterpret_cast<const bf16x8*>(&t2wf[((n0*16+8+kt)*64+lane)*8]);
        acc = MFMA(ab[kt], bw, acc);
      }
      int s = n0*16 + li;
      #pragma unroll
      for (int reg=0;reg<4;reg++){
        int row = lk*4 + reg;
        float hid = fmaxf(acc[reg], 0.f);
        float z = zS[row][s];
        float hn = (1.f - z)*hS[row][s] + z*hid;
        hS[row][s] = hn;
        hBf[row][s] = f2bf(hn);
        out[((b0+row)*128 + t)*256 + s] = hn;
      }
    }
    __syncthreads();                 // bar3: hS/hBf visible for next step
  }
}

// ---------------------------------------------------------------------------
extern "C" void kernel_launch(void* const* d_in, const int* in_sizes, int n_in,
                              void* d_out, int out_size, void* d_ws, size_t ws_size,
                              hipStream_t stream)
{
  const int*   ids  = (const int*)  d_in[0];
  // d_in[1] lengths: unused by forward
  const float* emb  = (const float*)d_in[2];
  const float* embr = (const float*)d_in[3];
  const float* gen  = (const float*)d_in[4];
  const float* Wss1 = (const float*)d_in[5];
  const float* Wrs1 = (const float*)d_in[6];
  const float* bs1  = (const float*)d_in[7];
  const float* Wss2 = (const float*)d_in[8];
  const float* Wrs2 = (const float*)d_in[9];
  const float* bs2  = (const float*)d_in[10];
  const float* beta = (const float*)d_in[11];
  const float* wild = (const float*)d_in[12];
  const float* tr1  = (const float*)d_in[13];
  const float* tr2  = (const float*)d_in[14];
  const float* h1   = (const float*)d_in[15];
  float* out = (float*)d_out;

  char* ws = (char*)d_ws;
  unsigned short* genf   = (unsigned short*)(ws + 0);         // 163840 B
  unsigned short* w12f   = (unsigned short*)(ws + 163840);    // 262144 B
  unsigned short* wrs12f = (unsigned short*)(ws + 425984);    // 262144 B
  unsigned short* tr1f   = (unsigned short*)(ws + 688128);    // 131072 B
  unsigned short* t2wf   = (unsigned short*)(ws + 819200);    // 262144 B
  unsigned short* LseqB  = (unsigned short*)(ws + 1081344);   // 33554432 B
  float*          U12    = (float*)         (ws + 34635776);  // 134217728 B
  // total ws use: 168,853,504 bytes

  prep_weights<<<264, 256, 0, stream>>>(Wss1, Wss2, Wrs1, Wrs2, tr1, tr2, wild, gen,
                                        genf, w12f, wrs12f, tr1f, t2wf);
  embed_lseq<<<1024, 256, 0, stream>>>(ids, emb, embr, beta, genf, LseqB);
  u12_gemm<<<1024, 256, 0, stream>>>(LseqB, wrs12f, bs1, bs2, U12);
  scan_kernel<<<32, 512, 0, stream>>>(LseqB, U12, w12f, tr1f, t2wf, h1, out);
}